// Round 1
// baseline (202.759 us; speedup 1.0000x reference)
//
#include <hip/hip_runtime.h>
#include <cstdint>

#define NCLS 3
#define NPTS 100000
#define NB 2
#define PRE 512
#define POST 100
#define SCORE_TH 0.1f
#define NMS_TH 0.25
#define CAP 1024            // candidate buffer per problem (expect ~690)
#define NBINS 384           // fast-key bins: (key>>17) - (0xBD000000>>17)
#define BIN_SH 17
#define BIN_OFFW (0xBD000000u >> BIN_SH)
#define FMARG 2e-5f         // 2x bound on |f32 sigmoid - f64 sigmoid| (<=1e-6)
#define NPROB (NB * NCLS)
#define WAVES_PER_PROB 2304  // 36 upper-tri 64x64 cells x 64 rows

// ---------------- ws layout (bytes) ---------------- (NO memset needed)
// mask      : uint64 [6*PRE*8]      @ 0         (196,608; upper-tri words
//                                                always stored by iou_fused;
//                                                lower-tri garbage harmless)
// cand_idx  : uint32 [6*PRE]        @ 196,608   (12,288)
// cand_scr  : float  [6*PRE]        @ 208,896   (12,288)
// boxdata   : double [6*PRE*20]     @ 221,184   (491,520)
// screen    : float  [6*PRE*8]      @ 712,704   (98,304)
// total ~811 KB (sf / hist_part / cand / pivots / cand_cnt all eliminated:
// the per-problem front half now runs block-local in LDS)

__device__ __forceinline__ uint32_t score_key(float x)
{
    // EXACT path: f64 sigmoid rounded to f32 == reference (absmax 0.0)
    double sd = 1.0 / (1.0 + exp(-(double)x));
    float s = (float)sd;
    if (!(s >= SCORE_TH)) s = -1.0f;
    uint32_t u = __float_as_uint(s);
    return (u & 0x80000000u) ? ~u : (u | 0x80000000u);
}

__device__ __forceinline__ float fast_sig(float x)
{
    return 1.0f / (1.0f + __expf(-x));
}

// monotone bin of a (possibly margin-adjusted) f32 score
__device__ __forceinline__ int fast_bin(float s)
{
    float v = (s >= SCORE_TH) ? s : -1.0f;
    uint32_t u = __float_as_uint(v);
    uint32_t kk = (u & 0x80000000u) ? ~u : (u | 0x80000000u);
    int b = (int)(kk >> BIN_SH) - (int)BIN_OFFW;
    return b < 0 ? 0 : (b > NBINS - 1 ? NBINS - 1 : b);
}

// Fused per-problem front half: histogram -> pivot -> compact -> sort ->
// epilogue, all block-local. One block = one (batch, class) problem.
// No global intermediates; cls is read twice (second pass L2-resident).
// fast_sig is recomputed in pass 2 -- same deterministic expression, same
// input => bit-identical to pass 1, so the FMARG pivot-margin logic holds.
__global__ __launch_bounds__(1024) void stage1_kernel(
    const float* __restrict__ cls, const float* __restrict__ boxes,
    uint32_t* __restrict__ cand_idx, float* __restrict__ cand_score,
    double* __restrict__ boxdata, float* __restrict__ screen)
{
    const int p = blockIdx.x;              // 0..5
    const int b = p / NCLS, k = p % NCLS;
    const int tid = threadIdx.x;

    __shared__ uint32_t hist[2][NBINS];    // 2 copies halve hot-bin chains
    __shared__ uint32_t suf[NBINS];
    __shared__ unsigned long long skey[CAP];
    __shared__ uint32_t lcnt;
    __shared__ uint32_t pivot_s;

    if (tid < NBINS) { hist[0][tid] = 0; hist[1][tid] = 0; }
    if (tid == 0) { lcnt = 0; pivot_s = 0; }
    __syncthreads();

    const float* cp = cls + (size_t)b * NPTS * NCLS + k;
    const int par = (tid >> 6) & 1;        // wave-parity histogram copy

    // ---- phase 1: histogram (identical binning to the old hist_kernel) ----
    for (int i = tid; i < NPTS; i += 1024) {
        float x = cp[(size_t)i * NCLS];
        atomicAdd(&hist[par][fast_bin(fast_sig(x))], 1u);
    }
    __syncthreads();

    // ---- phase 2: pivot = max bin with suffix-count >= PRE (same math as
    // the old top-down scan: cum=suf[bin+1]<PRE and cum+h=suf[bin]>=PRE) ----
    if (tid < NBINS) suf[tid] = hist[0][tid] + hist[1][tid];
    __syncthreads();
    for (int off = 1; off < NBINS; off <<= 1) {
        uint32_t v = 0;
        if (tid < NBINS && tid + off < NBINS) v = suf[tid + off];
        __syncthreads();
        if (tid < NBINS) suf[tid] += v;
        __syncthreads();
    }
    if (tid < NBINS && suf[tid] >= PRE &&
        (tid == NBINS - 1 || suf[tid + 1] < PRE))
        pivot_s = (uint32_t)tid;           // unique writer (suf monotone)
    __syncthreads();
    const uint32_t pb = pivot_s;           // 0 fallback if total < PRE

    // ---- phase 3: compact survivors into LDS (exact f64 key on survivors
    // only, ~690 per problem) ----
    for (int i = tid; i < NPTS; i += 1024) {
        float x = cp[(size_t)i * NCLS];
        float sfv = fast_sig(x);
        if ((uint32_t)fast_bin(sfv + FMARG) >= pb) {
            uint32_t kk = score_key(x);
            unsigned long long entry =
                ((unsigned long long)kk << 32) | (uint32_t)(~(uint32_t)i);
            uint32_t slot = atomicAdd(&lcnt, 1u);
            if (slot < CAP) skey[slot] = entry;
        }
    }
    __syncthreads();
    const uint32_t cnt = lcnt < CAP ? lcnt : CAP;
    for (uint32_t e = tid; e < CAP; e += 1024)
        if (e >= cnt) skey[e] = 0ull;      // pad: sorts below any real entry
    __syncthreads();

    // ---- phase 4: bitonic sort, descending. SAME network as before, but
    // value-in-register: j<=32 steps via __shfl_xor (intra-wave, no barrier),
    // only j>=64 steps via LDS => 10 LDS stages / 20 barriers vs 55. ----
    unsigned long long val = skey[tid];
    for (int k2 = 2; k2 <= CAP; k2 <<= 1) {
        const bool up = (tid & k2) == 0;   // k2==1024 -> always true
        for (int j = k2 >> 1; j >= 64; j >>= 1) {
            skey[tid] = val;
            __syncthreads();
            unsigned long long o = skey[tid ^ j];
            __syncthreads();
            const bool keepLarge = (((tid & j) == 0) == up);
            val = keepLarge ? (val >= o ? val : o) : (val <= o ? val : o);
        }
        int js = (k2 >> 1) < 32 ? (k2 >> 1) : 32;
        for (int j = js; j >= 1; j >>= 1) {
            unsigned long long o = __shfl_xor(val, j);
            const bool keepLarge = (((tid & j) == 0) == up);
            val = keepLarge ? (val >= o ? val : o) : (val <= o ? val : o);
        }
    }

    // ---- phase 5: top-512 decode + f64 geometry + f32 screen ----
    if (tid >= PRE) return;
    unsigned long long key = val;
    double* D = boxdata + (size_t)(p * PRE + tid) * 20;
    float* S = screen + (size_t)(p * PRE + tid) * 8;
    if (key == 0ull) {                     // defensive: can't happen normally
        cand_idx[p * PRE + tid] = 0;
        cand_score[p * PRE + tid] = -1.0f;
        #pragma unroll
        for (int m = 0; m < 20; ++m) D[m] = 0.0;
        #pragma unroll
        for (int m = 0; m < 8; ++m) S[m] = 0.0f;
        return;
    }
    uint32_t idx = ~((uint32_t)key);
    uint32_t ov = (uint32_t)(key >> 32);
    uint32_t ub = (ov & 0x80000000u) ? (ov ^ 0x80000000u) : ~ov;
    float sc = __uint_as_float(ub);
    cand_idx[p * PRE + tid] = idx;
    cand_score[p * PRE + tid] = sc;

    const float* bp = boxes + ((size_t)b * NPTS + idx) * 7;
    double x = bp[0], y = bp[1], z = bp[2];
    double dx = bp[3], dy = bp[4], dz = bp[5], r = bp[6];
    double c = cos(r), s = sin(r);
    double hx = 0.5 * dx, hy = 0.5 * dy;
    double zlo = z - 0.5 * dz, zhi = z + 0.5 * dz;
    double rad = sqrt(hx * hx + hy * hy);
    D[0] = x; D[1] = y; D[2] = c; D[3] = s; D[4] = hx; D[5] = hy;
    D[6] = zlo; D[7] = zhi; D[8] = dx * dy * dz; D[9] = rad;
    const double lxs[4] = { hx, -hx, -hx,  hx };
    const double lys[4] = { hy,  hy, -hy, -hy };
    #pragma unroll
    for (int m = 0; m < 4; ++m) {
        D[10 + m] = x + lxs[m] * c - lys[m] * s;
        D[14 + m] = y + lxs[m] * s + lys[m] * c;
    }
    S[0] = (float)x; S[1] = (float)y; S[2] = (float)zlo; S[3] = (float)zhi;
    S[4] = (float)rad; S[5] = 0.0f; S[6] = 0.0f; S[7] = 0.0f;
}

// Fused screen + exact IoU. One wave per (prob, cell, row): wave owns mask
// word (prob,i,wj) exclusively and ALWAYS stores it (even 0) -> mask needs
// no pre-zero. Lower-triangle words stay garbage: bits there mark columns
// j<i, which the greedy scan has already passed -- provably no effect.
// The <=24 candidate points live in lanes 0-23, so the sort/reductions run
// on 32-lane groups (15 bitonic stages, 5-step butterflies) not 64.
__global__ __launch_bounds__(256) void iou_fused_kernel(
    const float* __restrict__ screen, const double* __restrict__ boxdata,
    unsigned long long* __restrict__ mask)
{
    const int W = blockIdx.x * 4 + (threadIdx.x >> 6);
    const int lane = threadIdx.x & 63;
    const int prob = W / WAVES_PER_PROB;
    int t = W - prob * WAVES_PER_PROB;
    int cell = t >> 6, r = t & 63;
    int wi = 0;
    while (cell >= 8 - wi) { cell -= 8 - wi; ++wi; }
    const int wj = wi + cell;
    const int bi = wi * 64 + r;
    const int j = wj * 64 + lane;

    bool surv = false;
    {
        const float* SA = screen + (size_t)(prob * PRE + bi) * 8; // wave-uniform
        const float* SB = screen + (size_t)(prob * PRE + j) * 8;
        if (j > bi) {
            float4 a4 = *(const float4*)SA;           // x,y,zlo,zhi
            float4 b4 = *(const float4*)SB;
            float hz = fminf(a4.w, b4.w) - fmaxf(a4.z, b4.z);
            if (hz > 0.0f) {
                float ddx = a4.x - b4.x, ddy = a4.y - b4.y;
                float rs = SA[4] + SB[4] + 0.01f;
                surv = (ddx * ddx + ddy * ddy <= rs * rs);
            }
        }
    }
    unsigned long long sm = __ballot(surv);   // wave-uniform survivor set
    unsigned long long supw = 0ull;
    const double* A = boxdata + (size_t)(prob * PRE + bi) * 20;

    while (sm) {
        int jb = __ffsll(sm) - 1;
        sm &= sm - 1ull;
        const int bj = wj * 64 + jb;
        const double* B = boxdata + (size_t)(prob * PRE + bj) * 20;

        // lane owns one candidate point: 0-3 A-corners, 4-7 B-corners,
        // 8-23 edge intersections (reference construction order)
        double PX = 0.0, PY = 0.0;
        bool valid = false;
        if (lane < 8) {
            const double* S = (lane < 4) ? A : B;
            const double* O = (lane < 4) ? B : A;
            int m = lane & 3;
            PX = S[10 + m]; PY = S[14 + m];
            double rx = PX - O[0], ry = PY - O[1];
            double u =  rx * O[2] + ry * O[3];
            double v = -rx * O[3] + ry * O[2];
            valid = (fabs(u) <= O[4] + 1e-5) && (fabs(v) <= O[5] + 1e-5);
        } else if (lane < 24) {
            int e = lane - 8, m = e >> 2, nn = e & 3;
            double ax = A[10 + m], ay = A[14 + m];
            double rax = A[10 + ((m + 1) & 3)] - ax;
            double ray = A[14 + ((m + 1) & 3)] - ay;
            double bx = B[10 + nn], by = B[14 + nn];
            double rbx = B[10 + ((nn + 1) & 3)] - bx;
            double rby = B[14 + ((nn + 1) & 3)] - by;
            double d = rax * rby - ray * rbx;
            if (fabs(d) > 1e-8) {
                double qx = bx - ax, qy = by - ay;
                double tt = (qx * rby - qy * rbx) / d;
                double uu = (qx * ray - qy * rax) / d;
                valid = (tt >= 0.0 && tt <= 1.0 && uu >= 0.0 && uu <= 1.0);
                PX = ax + tt * rax; PY = ay + tt * ray;
            }
        }
        if (!valid) { PX = 0.0; PY = 0.0; }

        unsigned long long bal = __ballot(valid);  // valid only in lanes 0-23
        int cnt = __popcll(bal);
        double sx = PX, sy = PY;          // invalid lanes contribute 0
        #pragma unroll
        for (int off = 16; off; off >>= 1) {       // 32-group butterfly
            sx += __shfl_xor(sx, off);
            sy += __shfl_xor(sy, off);
        }
        int cdiv = cnt > 0 ? cnt : 1;     // ref: / max(cnt, 1)
        double cxc = sx / cdiv, cyc = sy / cdiv;

        double ang = valid ? atan2(PY - cyc, PX - cxc) : 1e9;
        int sidx = lane;                  // construction order == ref slots

        // 32-lane bitonic sort asc by (ang, sidx) == numpy stable argsort
        #pragma unroll
        for (int k = 2; k <= 32; k <<= 1) {
            #pragma unroll
            for (int jj = k >> 1; jj > 0; jj >>= 1) {
                double oang = __shfl_xor(ang, jj);
                double opx  = __shfl_xor(PX, jj);
                double opy  = __shfl_xor(PY, jj);
                int    oidx = __shfl_xor(sidx, jj);
                bool iLow = (lane & jj) == 0;
                bool dirUp = (lane & k) == 0;
                bool mineFirst = (ang < oang) || (ang == oang && sidx < oidx);
                bool keepMine = (mineFirst == (iLow == dirUp));
                if (!keepMine) { ang = oang; PX = opx; PY = opy; sidx = oidx; }
            }
        }

        // centered shoelace over sorted lanes [0, cnt)  (cnt <= 24 < 32)
        double nxp = __shfl(PX, (lane + 1) & 31);
        double nyp = __shfl(PY, (lane + 1) & 31);
        double fx  = __shfl(PX, 0);
        double fy  = __shfl(PY, 0);
        bool last = (lane == cnt - 1);
        double qx = last ? fx : nxp, qy = last ? fy : nyp;
        double contrib = 0.0;
        if (lane < cnt)
            contrib = (PX - cxc) * (qy - cyc) - (PY - cyc) * (qx - cxc);
        #pragma unroll
        for (int off = 16; off; off >>= 1) contrib += __shfl_xor(contrib, off);
        double inter = (cnt >= 3) ? 0.5 * fabs(contrib) : 0.0;

        if (lane == 0) {
            double zt = fmin(A[7], B[7]);
            double zb = fmax(A[6], B[6]);
            double hz = zt - zb;
            bool sup = false;
            if (hz > 0.0) {
                double i3 = inter * hz;
                double den = A[8] + B[8] - i3;
                if (den < 1e-8) den = 1e-8;
                sup = (i3 / den) > (double)NMS_TH;
            }
            if (sup) supw |= 1ull << jb;
        }
    }

    if (lane == 0)
        mask[(size_t)(prob * PRE + bi) * 8 + wj] = supw;   // exclusive word
}

__global__ __launch_bounds__(256) void nms_out_kernel(
    const float* __restrict__ boxes, const uint32_t* __restrict__ cand_idx,
    const float* __restrict__ cand_score,
    const unsigned long long* __restrict__ mask, float* __restrict__ out)
{
    const int p = blockIdx.x;
    const int b = p / NCLS, k = p % NCLS;
    const int tid = threadIdx.x;

    __shared__ unsigned long long smask[PRE * 8];   // 32 KB
    __shared__ float sscore[PRE];
    __shared__ int slist[POST];
    __shared__ int scnt;

    for (int w = tid; w < PRE * 8; w += 256)
        smask[w] = mask[(size_t)p * PRE * 8 + w];
    for (int i = tid; i < PRE; i += 256)
        sscore[i] = cand_score[p * PRE + i];
    __syncthreads();

    // Wave-parallel greedy scan; early break at c==POST. Garbage bits in
    // lower-triangle mask words only mark columns j<i (already processed)
    // and cannot change any keep decision.
    if (tid < 64) {
        const int lane = tid;
        uint32_t supbits = 0;
        int c = 0;
        for (int i = 0; i < PRE; ++i) {
            uint32_t sb = (uint32_t)__shfl((int)supbits, i & 63);
            bool sup_i = (sb >> (i >> 6)) & 1u;
            float sc = sscore[i];                      // LDS broadcast
            bool keep = (sc >= SCORE_TH) && !sup_i;    // wave-uniform
            if (keep) {
                if (lane == 0) slist[c] = i;
                ++c;
                if (c >= POST) break;
                #pragma unroll
                for (int w = 0; w < 8; ++w) {
                    unsigned long long m = smask[i * 8 + w];  // broadcast
                    supbits |= (uint32_t)((m >> lane) & 1ull) << w;
                }
            }
        }
        if (lane == 0) scnt = c;
    }
    __syncthreads();

    const int cnt = scnt;
    for (int t = tid; t < POST; t += 256) {
        int row = b * (NCLS * POST) + k * POST + t;          // 0..599
        float* ob = out + (size_t)row * 7;
        float* os = out + (size_t)NB * NCLS * POST * 7 + row;
        float* ol = out + (size_t)NB * NCLS * POST * 7 + (size_t)NB * NCLS * POST + row;
        if (t < cnt) {
            int r = slist[t];
            uint32_t idx = cand_idx[p * PRE + r];
            const float* bp = boxes + ((size_t)b * NPTS + idx) * 7;
            #pragma unroll
            for (int c7 = 0; c7 < 7; ++c7) ob[c7] = bp[c7];
            *os = sscore[r];
            *ol = (float)(k + 1);
        } else {
            #pragma unroll
            for (int c7 = 0; c7 < 7; ++c7) ob[c7] = 0.0f;
            *os = 0.0f;
            *ol = 0.0f;
        }
    }
}

extern "C" void kernel_launch(void* const* d_in, const int* in_sizes, int n_in,
                              void* d_out, int out_size, void* d_ws, size_t ws_size,
                              hipStream_t stream)
{
    (void)in_sizes; (void)n_in; (void)out_size; (void)ws_size;
    const float* cls   = (const float*)d_in[0];   // (2,100000,3) f32
    const float* boxes = (const float*)d_in[1];   // (2,100000,7) f32
    float* out = (float*)d_out;

    char* ws = (char*)d_ws;
    unsigned long long* mask = (unsigned long long*)(ws);
    uint32_t* cand_idx    = (uint32_t*)(ws + 196608);
    float*    cand_score  = (float*)   (ws + 208896);
    double*   boxdata     = (double*)  (ws + 221184);
    float*    screen      = (float*)   (ws + 712704);

    // 3 kernels (was 6): front half fused per-problem, no global
    // intermediates, no memsets (mask upper-tri fully written by iou_fused).
    hipLaunchKernelGGL(stage1_kernel, dim3(NPROB), dim3(1024), 0, stream,
                       cls, boxes, cand_idx, cand_score, boxdata, screen);
    hipLaunchKernelGGL(iou_fused_kernel, dim3(NPROB * WAVES_PER_PROB / 4),
                       dim3(256), 0, stream, screen, boxdata, mask);
    hipLaunchKernelGGL(nms_out_kernel, dim3(NPROB), dim3(256), 0, stream,
                       boxes, cand_idx, cand_score, mask, out);
}